// Round 1
// baseline (462.411 us; speedup 1.0000x reference)
//
#include <hip/hip_runtime.h>
#include <hip/hip_bf16.h>
#include <stdint.h>

#define TOKENS 8192
#define NF 4096   // out features
#define KF 4096   // in features
#define RANK 16

typedef __attribute__((ext_vector_type(8))) short bf16x8;
typedef __attribute__((ext_vector_type(4))) float f32x4;
typedef __attribute__((ext_vector_type(8))) unsigned short u16x8;

static __device__ __forceinline__ unsigned short f2b(float f) {
    union { float f; uint32_t u; } v; v.f = f;
    uint32_t u = v.u;
    uint32_t r = (u + 0x7fffu + ((u >> 16) & 1u)) >> 16;   // RNE
    return (unsigned short)r;
}

// Wt[n][k] = bf16( W[k][n] + sum_r U[k][r]*s[r]*Vt[r][n] )  (transposed, K-contiguous)
__global__ __launch_bounds__(256) void prep_w_kernel(
    const float* __restrict__ W, const float* __restrict__ U,
    const float* __restrict__ s, const float* __restrict__ Vt,
    unsigned short* __restrict__ Wt)
{
    __shared__ float Us[64][16];
    __shared__ float Vs[16][64];
    __shared__ float tile[64][65];
    const int kb = blockIdx.x, nb = blockIdx.y;
    const int t = threadIdx.x;
    for (int idx = t; idx < 64 * 16; idx += 256) {
        int kl = idx >> 4, r = idx & 15;
        Us[kl][r] = U[(size_t)(kb * 64 + kl) * RANK + r];
    }
    for (int idx = t; idx < 16 * 64; idx += 256) {
        int r = idx >> 6, nl = idx & 63;
        Vs[r][nl] = Vt[(size_t)r * NF + nb * 64 + nl] * s[r];
    }
    __syncthreads();
    const int nl = t & 63, kl0 = t >> 6;
    for (int i = 0; i < 16; ++i) {
        int kl = kl0 + i * 4;
        float v = W[(size_t)(kb * 64 + kl) * NF + nb * 64 + nl];
        #pragma unroll
        for (int r = 0; r < RANK; ++r) v += Us[kl][r] * Vs[r][nl];
        tile[kl][nl] = v;
    }
    __syncthreads();
    const int klw = t & 63, nl0 = t >> 6;
    for (int i = 0; i < 16; ++i) {
        int nlw = nl0 + i * 4;
        Wt[(size_t)(nb * 64 + nlw) * KF + kb * 64 + klw] = f2b(tile[klw][nlw]);
    }
}

// xb[m][k] = bf16(x[m][k]) — vectorized cast
__global__ __launch_bounds__(256) void prep_x_kernel(
    const float* __restrict__ x, unsigned short* __restrict__ xb)
{
    size_t base = ((size_t)blockIdx.x * 256 + threadIdx.x) * 8;
    float4 a = *(const float4*)(x + base);
    float4 b = *(const float4*)(x + base + 4);
    u16x8 o;
    o[0] = f2b(a.x); o[1] = f2b(a.y); o[2] = f2b(a.z); o[3] = f2b(a.w);
    o[4] = f2b(b.x); o[5] = f2b(b.y); o[6] = f2b(b.z); o[7] = f2b(b.w);
    *(u16x8*)(xb + base) = o;
}

// m97-structure GEMM: 128x128 tile, BK=64, 4 waves, global_load_lds(16B),
// 2-barrier K-loop, 16x16x32 bf16 MFMA, 4x4 frags/wave.
// A = xb [TOKENS][KF] row-major; Bt = Wt [NF][KF] row-major (B transposed).
__global__ __launch_bounds__(256) void gemm_kernel(
    const unsigned short* __restrict__ A,
    const unsigned short* __restrict__ Bt,
    float* __restrict__ C)
{
    __shared__ __align__(16) unsigned short Asb[128 * 64];
    __shared__ __align__(16) unsigned short Bsb[128 * 64];

    // XCD-aware swizzle (2048 blocks, 2048 % 8 == 0 -> simple form is bijective)
    const int nwg = gridDim.x;
    const int cpx = nwg >> 3;
    const int bid = blockIdx.x;
    const int swz = (bid & 7) * cpx + (bid >> 3);
    const int TN = NF / 128;                 // 32
    const int tm = swz / TN, tn = swz % TN;

    const int tid = threadIdx.x;
    const int lane = tid & 63, wave = tid >> 6;
    const int wr = wave >> 1, wc = wave & 1; // wave -> 64x64 quadrant
    const int frow = lane & 15;
    const int kgrp = lane >> 4;

    f32x4 acc[4][4] = {};

    // staging: thread tid loads 16B; LDS linear [row][k], row = tid/8 (+32/round)
    const int st_row = tid >> 3;
    const int st_k = (tid & 7) * 8;
    const unsigned short* aSrc = A + (size_t)(tm * 128 + st_row) * KF + st_k;
    const unsigned short* bSrc = Bt + (size_t)(tn * 128 + st_row) * KF + st_k;
    unsigned short* aDst = Asb + wave * 512;   // wave-uniform base; HW adds lane*16B
    unsigned short* bDst = Bsb + wave * 512;

    for (int kt = 0; kt < KF / 64; ++kt) {
        __syncthreads();                       // prev compute done before overwrite
        const unsigned short* ag = aSrc + kt * 64;
        const unsigned short* bg = bSrc + kt * 64;
        #pragma unroll
        for (int r = 0; r < 4; ++r) {
            __builtin_amdgcn_global_load_lds(
                (const __attribute__((address_space(1))) void*)(ag + (size_t)r * 32 * KF),
                (__attribute__((address_space(3))) void*)(aDst + r * 2048),
                16, 0, 0);
            __builtin_amdgcn_global_load_lds(
                (const __attribute__((address_space(1))) void*)(bg + (size_t)r * 32 * KF),
                (__attribute__((address_space(3))) void*)(bDst + r * 2048),
                16, 0, 0);
        }
        __syncthreads();                       // compiler drains vmcnt before barrier
        #pragma unroll
        for (int kk = 0; kk < 2; ++kk) {
            bf16x8 a[4], b[4];
            #pragma unroll
            for (int i = 0; i < 4; ++i)
                a[i] = *(const bf16x8*)&Asb[(wr * 64 + i * 16 + frow) * 64 + kk * 32 + kgrp * 8];
            #pragma unroll
            for (int j = 0; j < 4; ++j)
                b[j] = *(const bf16x8*)&Bsb[(wc * 64 + j * 16 + frow) * 64 + kk * 32 + kgrp * 8];
            #pragma unroll
            for (int i = 0; i < 4; ++i)
                #pragma unroll
                for (int j = 0; j < 4; ++j)
                    acc[i][j] = __builtin_amdgcn_mfma_f32_16x16x32_bf16(a[i], b[j], acc[i][j], 0, 0, 0);
        }
    }

    // C/D layout: col = lane&15, row = (lane>>4)*4 + reg   [m89-verified]
    const int rgrp = lane >> 4;
    const int coll = lane & 15;
    #pragma unroll
    for (int i = 0; i < 4; ++i)
        #pragma unroll
        for (int j = 0; j < 4; ++j) {
            size_t row0 = (size_t)(tm * 128 + wr * 64 + i * 16 + rgrp * 4);
            size_t col = (size_t)(tn * 128 + wc * 64 + j * 16 + coll);
            #pragma unroll
            for (int r = 0; r < 4; ++r)
                C[(row0 + r) * NF + col] = acc[i][j][r];
        }
}

extern "C" void kernel_launch(void* const* d_in, const int* in_sizes, int n_in,
                              void* d_out, int out_size, void* d_ws, size_t ws_size,
                              hipStream_t stream) {
    const float* x  = (const float*)d_in[0];
    const float* W  = (const float*)d_in[1];
    const float* U  = (const float*)d_in[2];
    const float* s  = (const float*)d_in[3];
    const float* Vt = (const float*)d_in[4];
    float* out = (float*)d_out;

    unsigned short* Wt = (unsigned short*)d_ws;                  // 4096*4096*2 = 32 MB
    unsigned short* xb = Wt + (size_t)NF * KF;                   // 8192*4096*2 = 64 MB

    prep_w_kernel<<<dim3(KF / 64, NF / 64), 256, 0, stream>>>(W, U, s, Vt, Wt);
    prep_x_kernel<<<(TOKENS * KF / 8) / 256, 256, 0, stream>>>(x, xb);
    gemm_kernel<<<(TOKENS / 128) * (NF / 128), 256, 0, stream>>>(xb, Wt, out);
}

// Round 2
// 299.280 us; speedup vs baseline: 1.5451x; 1.5451x over previous
//
#include <hip/hip_runtime.h>
#include <hip/hip_bf16.h>
#include <stdint.h>

#define TOKENS 8192
#define NF 4096   // out features
#define KF 4096   // in features
#define RANK 16

typedef __attribute__((ext_vector_type(8))) short bf16x8;
typedef __attribute__((ext_vector_type(4))) float f32x4;
typedef __attribute__((ext_vector_type(8))) unsigned short u16x8;

static __device__ __forceinline__ unsigned short f2b(float f) {
    union { float f; uint32_t u; } v; v.f = f;
    uint32_t u = v.u;
    uint32_t r = (u + 0x7fffu + ((u >> 16) & 1u)) >> 16;   // RNE
    return (unsigned short)r;
}

// Wt[n][k] = bf16( W[k][n] + sum_r U[k][r]*s[r]*Vt[r][n] )  (transposed, K-contiguous)
__global__ __launch_bounds__(256) void prep_w_kernel(
    const float* __restrict__ W, const float* __restrict__ U,
    const float* __restrict__ s, const float* __restrict__ Vt,
    unsigned short* __restrict__ Wt)
{
    __shared__ float Us[64][16];
    __shared__ float Vs[16][64];
    __shared__ float tile[64][65];
    const int kb = blockIdx.x, nb = blockIdx.y;
    const int t = threadIdx.x;
    for (int idx = t; idx < 64 * 16; idx += 256) {
        int kl = idx >> 4, r = idx & 15;
        Us[kl][r] = U[(size_t)(kb * 64 + kl) * RANK + r];
    }
    for (int idx = t; idx < 16 * 64; idx += 256) {
        int r = idx >> 6, nl = idx & 63;
        Vs[r][nl] = Vt[(size_t)r * NF + nb * 64 + nl] * s[r];
    }
    __syncthreads();
    const int nl = t & 63, kl0 = t >> 6;
    for (int i = 0; i < 16; ++i) {
        int kl = kl0 + i * 4;
        float v = W[(size_t)(kb * 64 + kl) * NF + nb * 64 + nl];
        #pragma unroll
        for (int r = 0; r < RANK; ++r) v += Us[kl][r] * Vs[r][nl];
        tile[kl][nl] = v;
    }
    __syncthreads();
    const int klw = t & 63, nl0 = t >> 6;
    for (int i = 0; i < 16; ++i) {
        int nlw = nl0 + i * 4;
        Wt[(size_t)(nb * 64 + nlw) * KF + kb * 64 + klw] = f2b(tile[klw][nlw]);
    }
}

__global__ __launch_bounds__(256) void prep_x_kernel(
    const float* __restrict__ x, unsigned short* __restrict__ xb)
{
    size_t base = ((size_t)blockIdx.x * 256 + threadIdx.x) * 8;
    float4 a = *(const float4*)(x + base);
    float4 b = *(const float4*)(x + base + 4);
    u16x8 o;
    o[0] = f2b(a.x); o[1] = f2b(a.y); o[2] = f2b(a.z); o[3] = f2b(a.w);
    o[4] = f2b(b.x); o[5] = f2b(b.y); o[6] = f2b(b.z); o[7] = f2b(b.w);
    *(u16x8*)(xb + base) = o;
}

// ---------------------------------------------------------------------------
// 256x256 8-phase GEMM (plain-HIP port of the m201 template).
// A = xb [TOKENS][KF] rm; Bt = Wt [NF][KF] rm. 512 thr = 8 waves (2M x 4N).
// LDS 128 KiB = {A,B} x {dbuf0,1} x {half0,1} x [128][64] bf16, XOR-swizzled
// via pre-swizzled global source cols (linear global_load_lds dest).
// Phase->stage map (iter i, kt1=2i+1, kt2=2i+2, kt3=2i+3):
//   P1:A[1][0]kt1 P2:A[1][1]kt1 P3:B[0][0]kt2 P4:B[0][1]kt2+vmcnt(4)
//   P5:A[0][0]kt2 P6:A[0][1]kt2 P7:B[1][0]kt3 P8:B[1][1]kt3+vmcnt(4)
// Every region is staged in the phase AFTER its last reader (WAR-safe via the
// two-barrier phase), and every region's data is vmcnt-drained before use.
// ---------------------------------------------------------------------------

#define VM4  asm volatile("s_waitcnt vmcnt(4)" ::: "memory")
#define NOVM

#define PHASE(d, q, bfr, STAGE_STMT, VMW) do {                                  \
    bf16x8 af0k0 = ldA(d, 2*(q), 0),   af0k1 = ldA(d, 2*(q), 1);                \
    bf16x8 af1k0 = ldA(d, 2*(q)+1, 0), af1k1 = ldA(d, 2*(q)+1, 1);              \
    STAGE_STMT;                                                                 \
    VMW;                                                                        \
    __builtin_amdgcn_s_barrier();                                               \
    asm volatile("s_waitcnt lgkmcnt(0)" ::: "memory");                          \
    __builtin_amdgcn_s_setprio(1);                                              \
    _Pragma("unroll")                                                           \
    for (int nf = 0; nf < 4; ++nf) {                                            \
        acc[2*(q)][nf]   = __builtin_amdgcn_mfma_f32_16x16x32_bf16(af0k0, bfr[nf][0], acc[2*(q)][nf],   0,0,0); \
        acc[2*(q)][nf]   = __builtin_amdgcn_mfma_f32_16x16x32_bf16(af0k1, bfr[nf][1], acc[2*(q)][nf],   0,0,0); \
        acc[2*(q)+1][nf] = __builtin_amdgcn_mfma_f32_16x16x32_bf16(af1k0, bfr[nf][0], acc[2*(q)+1][nf], 0,0,0); \
        acc[2*(q)+1][nf] = __builtin_amdgcn_mfma_f32_16x16x32_bf16(af1k1, bfr[nf][1], acc[2*(q)+1][nf], 0,0,0); \
    }                                                                           \
    __builtin_amdgcn_s_setprio(0);                                              \
    __builtin_amdgcn_s_barrier();                                               \
} while (0)

#define LDB_ALL(d, bfr) do {                                                    \
    _Pragma("unroll")                                                           \
    for (int nf = 0; nf < 4; ++nf) {                                            \
        bfr[nf][0] = ldB(d, nf, 0);                                             \
        bfr[nf][1] = ldB(d, nf, 1);                                             \
    } } while (0)

__global__ __launch_bounds__(512, 2) void gemm_kernel(
    const unsigned short* __restrict__ A,
    const unsigned short* __restrict__ Bt,
    float* __restrict__ C)
{
    __shared__ __align__(16) unsigned short lds[65536];   // 128 KiB

    const int tid  = threadIdx.x;
    const int lane = tid & 63;
    const int wave = tid >> 6;
    const int wm = wave >> 2;          // 0..1
    const int wn = wave & 3;           // 0..3

    // XCD-aware swizzle: 512 blocks, 512 % 8 == 0 -> bijective
    const int bid = blockIdx.x;
    const int swz = (bid & 7) * 64 + (bid >> 3);
    const int tm = swz >> 4;           // 32 M-tiles
    const int tn = swz & 15;           // 16 N-tiles

    const int frow = lane & 15;
    const int kgrp = lane >> 4;
    const int xorv = (frow & 7) << 4;  // read-side byte XOR (bits 4-6)

    // staging: thread tid covers LDS bytes [tid*16, tid*16+16) (+8KB for l=1).
    // source col is pre-swizzled with the same involution so LDS stays linear.
    const int st_row  = tid >> 3;                                       // 0..63
    const int st_colE = ((((tid & 7) * 16) ^ (((tid >> 3) & 7) << 4)) >> 1); // elems
    const unsigned short* aSrc = A  + (size_t)(tm * 256 + st_row) * KF + st_colE;
    const unsigned short* bSrc = Bt + (size_t)(tn * 256 + st_row) * KF + st_colE;
    const int dstE = tid * 8;

    f32x4 acc[8][4] = {};

    // stage one half-tile (128 rows x 64 cols bf16 = 2 global_load_lds/thread)
    auto stage = [&](int isB, int d, int h, int kt) {
        const unsigned short* src =
            (isB ? bSrc : aSrc) + (size_t)((h) * 128) * KF + (kt) * 64;
        unsigned short* dst = (unsigned short*)&lds[isB * 32768 + (d * 2 + h) * 8192 + dstE];
        __builtin_amdgcn_global_load_lds(
            (const __attribute__((address_space(1))) void*)src,
            (__attribute__((address_space(3))) void*)dst, 16, 0, 0);
        __builtin_amdgcn_global_load_lds(
            (const __attribute__((address_space(1))) void*)(src + (size_t)64 * KF),
            (__attribute__((address_space(3))) void*)(dst + 4096), 16, 0, 0);
    };

    // swizzled LDS frag reads (ds_read_b128, conflict-free after XOR)
    auto ldA = [&](int d, int mf, int kk) -> bf16x8 {
        int off = (d * 2 + wm) * 8192 + (mf * 16 + frow) * 64
                + ((((kk << 6) | (kgrp << 4)) ^ xorv) >> 1);
        return *(const bf16x8*)&lds[off];
    };
    auto ldB = [&](int d, int nf, int kk) -> bf16x8 {
        int off = 32768 + (d * 2 + (wn >> 1)) * 8192
                + ((wn & 1) * 64 + nf * 16 + frow) * 64
                + ((((kk << 6) | (kgrp << 4)) ^ xorv) >> 1);
        return *(const bf16x8*)&lds[off];
    };

    // ---- prologue: B[0][*](K0), A[0][*](K0), then B[1][*](K1) ----
    stage(1, 0, 0, 0); stage(1, 0, 1, 0);
    stage(0, 0, 0, 0); stage(0, 0, 1, 0);
    stage(1, 1, 0, 1); stage(1, 1, 1, 1);
    VM4;                               // drain K0 tiles; keep B[1](K1) in flight
    __builtin_amdgcn_s_barrier();

    // ---- main loop: 64 K-tiles, 2 per iteration ----
    for (int i = 0; i < 32; ++i) {
        const int kt1 = 2 * i + 1;
        const int kt2 = (2 * i + 2) & 63;   // wrap on last iter (dead data, safe)
        const int kt3 = (2 * i + 3) & 63;

        bf16x8 bfr[4][2];
        LDB_ALL(0, bfr);
        PHASE(0, 0, bfr, stage(0, 1, 0, kt1), NOVM);
        PHASE(0, 1, bfr, stage(0, 1, 1, kt1), NOVM);
        PHASE(0, 2, bfr, stage(1, 0, 0, kt2), NOVM);
        PHASE(0, 3, bfr, stage(1, 0, 1, kt2), VM4);
        LDB_ALL(1, bfr);
        PHASE(1, 0, bfr, stage(0, 0, 0, kt2), NOVM);
        PHASE(1, 1, bfr, stage(0, 0, 1, kt2), NOVM);
        PHASE(1, 2, bfr, stage(1, 1, 0, kt3), NOVM);
        PHASE(1, 3, bfr, stage(1, 1, 1, kt3), VM4);
    }

    // drain remaining prefetches before LDS goes out of scope at wave exit
    asm volatile("s_waitcnt vmcnt(0)" ::: "memory");

    // ---- epilogue: C/D layout col=lane&15, row=(lane>>4)*4+reg ----
    const int rgrp = lane >> 4, coll = lane & 15;
    #pragma unroll
    for (int mf = 0; mf < 8; ++mf)
        #pragma unroll
        for (int nf = 0; nf < 4; ++nf) {
            size_t row0 = (size_t)(tm * 256 + wm * 128 + mf * 16 + rgrp * 4);
            size_t col  = (size_t)(tn * 256 + wn * 64 + nf * 16 + coll);
            #pragma unroll
            for (int r = 0; r < 4; ++r)
                C[(row0 + r) * NF + col] = acc[mf][nf][r];
        }
}

extern "C" void kernel_launch(void* const* d_in, const int* in_sizes, int n_in,
                              void* d_out, int out_size, void* d_ws, size_t ws_size,
                              hipStream_t stream) {
    const float* x  = (const float*)d_in[0];
    const float* W  = (const float*)d_in[1];
    const float* U  = (const float*)d_in[2];
    const float* s  = (const float*)d_in[3];
    const float* Vt = (const float*)d_in[4];
    float* out = (float*)d_out;

    unsigned short* Wt = (unsigned short*)d_ws;                  // 32 MB
    unsigned short* xb = Wt + (size_t)NF * KF;                   // 64 MB

    prep_w_kernel<<<dim3(KF / 64, NF / 64), 256, 0, stream>>>(W, U, s, Vt, Wt);
    prep_x_kernel<<<(TOKENS * KF / 8) / 256, 256, 0, stream>>>(x, xb);
    gemm_kernel<<<(TOKENS / 256) * (NF / 256), 512, 0, stream>>>(xb, Wt, out);
}